// Round 13
// baseline (93.281 us; speedup 1.0000x reference)
//
#include <hip/hip_runtime.h>
#include <math.h>

#define KCONST 0.1f
#define GAMMA_C 1.0f
#define D_DIM 128

typedef __attribute__((ext_vector_type(4))) float f32x4;

#define ASYNC_COPY16(gsrc, ldst)                                                  \
  __builtin_amdgcn_global_load_lds(                                               \
      (const __attribute__((address_space(1))) void*)(gsrc),                      \
      (__attribute__((address_space(3))) void*)(ldst), 16, 0, 0)

#define FP8_SCALE 16.0f       // inputs scaled x16 before e4m3 quantization
#define INV_TWO_OVER_SQ 0.0078125f  // 2/256

// pack 4 floats -> 4 fp8 e4m3 bytes (one dword)
__device__ __forceinline__ int pk_fp8x4(float a, float b, float c, float d) {
  int v = __builtin_amdgcn_cvt_pk_fp8_f32(a, b, 0, 0);
  v = __builtin_amdgcn_cvt_pk_fp8_f32(c, d, v, 1);
  return v;
}

// ---------------------------------------------------------------------------
// prep_x: 256 blocks. 16 lanes/row (8 elems each), 4 rows/wave-iter, 4 iters.
// Converts x -> fp8 e4m3 (x16 scale), writes nx2p[row]=1+||x||^2, per-block
// partial col-sums + sum(nx2). Block 0 zeroes out[0].
// ---------------------------------------------------------------------------
__global__ void prep_x(const float* __restrict__ x, unsigned char* __restrict__ xb,
                       float* __restrict__ nx2p, float* __restrict__ pSumX,
                       float* __restrict__ pS2, float* __restrict__ out_zero, int N) {
  if (blockIdx.x == 0 && threadIdx.x == 0) *out_zero = 0.f;
  const int tid = threadIdx.x;
  const int l = tid & 63, w = tid >> 6;
  const int l16 = l & 15, sub = l >> 4;
  const int waveId = blockIdx.x * 4 + w;  // 0..1023
  const float4* x4 = (const float4*)x;
  float4 c0 = {0.f, 0.f, 0.f, 0.f}, c1 = {0.f, 0.f, 0.f, 0.f};
  float s2 = 0.f;
#pragma unroll
  for (int it = 0; it < 4; ++it) {
    int row = (waveId + it * 1024) * 4 + sub;
    float4 v0 = x4[row * 32 + 2 * l16];      // elems 8*l16 .. +3
    float4 v1 = x4[row * 32 + 2 * l16 + 1];  // elems 8*l16+4 .. +7
    c0.x += v0.x; c0.y += v0.y; c0.z += v0.z; c0.w += v0.w;
    c1.x += v1.x; c1.y += v1.y; c1.z += v1.z; c1.w += v1.w;
    int2 st;
    st.x = pk_fp8x4(v0.x * FP8_SCALE, v0.y * FP8_SCALE, v0.z * FP8_SCALE, v0.w * FP8_SCALE);
    st.y = pk_fp8x4(v1.x * FP8_SCALE, v1.y * FP8_SCALE, v1.z * FP8_SCALE, v1.w * FP8_SCALE);
    *(int2*)(xb + (size_t)row * 128 + 8 * l16) = st;
    float sq = v0.x * v0.x;
    sq = fmaf(v0.y, v0.y, sq); sq = fmaf(v0.z, v0.z, sq); sq = fmaf(v0.w, v0.w, sq);
    sq = fmaf(v1.x, v1.x, sq); sq = fmaf(v1.y, v1.y, sq);
    sq = fmaf(v1.z, v1.z, sq); sq = fmaf(v1.w, v1.w, sq);
    sq += __shfl_down(sq, 8); sq += __shfl_down(sq, 4);
    sq += __shfl_down(sq, 2); sq += __shfl_down(sq, 1);
    if (l16 == 0) {
      nx2p[row] = 1.f + sq;
      s2 += sq;
    }
  }
  s2 += __shfl_down(s2, 16);
  s2 += __shfl_down(s2, 32);
  __shared__ float cs[128];
  __shared__ float s2w[4];
  if (tid < 128) cs[tid] = 0.f;
  if (l == 0) s2w[w] = s2;
  __syncthreads();
  atomicAdd(&cs[8 * l16 + 0], c0.x); atomicAdd(&cs[8 * l16 + 1], c0.y);
  atomicAdd(&cs[8 * l16 + 2], c0.z); atomicAdd(&cs[8 * l16 + 3], c0.w);
  atomicAdd(&cs[8 * l16 + 4], c1.x); atomicAdd(&cs[8 * l16 + 5], c1.y);
  atomicAdd(&cs[8 * l16 + 6], c1.z); atomicAdd(&cs[8 * l16 + 7], c1.w);
  __syncthreads();
  if (tid < 128) pSumX[blockIdx.x * 128 + tid] = cs[tid];
  if (tid == 0) pS2[blockIdx.x] = s2w[0] + s2w[1] + s2w[2] + s2w[3];
}

// ---------------------------------------------------------------------------
// merge_sums: 1 block x 1024 threads; 8-way segmented unrolled loads (MLP).
// ---------------------------------------------------------------------------
__global__ void merge_sums(const float* __restrict__ pSumX, const float* __restrict__ pS2,
                           float* __restrict__ sum_x, float* __restrict__ sum_nx2) {
  __shared__ float seg[8][128];
  __shared__ float s2w[4];
  const int t = threadIdx.x;       // 0..1023
  const int col = t & 127;
  const int sg = t >> 7;           // 0..7
  float s = 0.f;
#pragma unroll
  for (int b = 0; b < 32; ++b) s += pSumX[(sg * 32 + b) * 128 + col];
  seg[sg][col] = s;
  float s2 = (t < 256) ? pS2[t] : 0.f;
  if (t < 256) {
#pragma unroll
    for (int off = 32; off; off >>= 1) s2 += __shfl_down(s2, off);
    if ((t & 63) == 0) s2w[t >> 6] = s2;
  }
  __syncthreads();
  if (t < 128) {
    float r = 0.f;
#pragma unroll
    for (int k = 0; k < 8; ++k) r += seg[k][col];
    sum_x[t] = r;
  }
  if (t == 0) sum_nx2[0] = s2w[0] + s2w[1] + s2w[2] + s2w[3];
}

// ---------------------------------------------------------------------------
// prep_p: 128 blocks, 16 rows/block (16 lanes x 8 elems per row).
// Converts p -> fp8 e4m3 (x16); packs colc[j] =
// (Ac/256, Bc, np2, 256*Tc) with Ac=(1+np2)*cfi, Bc=np2*cfi, Tc=np2/(1+np2);
// psiA[j] = psi.
// ---------------------------------------------------------------------------
__global__ void prep_p(const float* __restrict__ p, unsigned char* __restrict__ pb,
                       const float* __restrict__ sum_x, const float* __restrict__ sum_nx2,
                       float4* __restrict__ colc, float* __restrict__ psiA,
                       int M, int N) {
  const int tid = threadIdx.x;
  const int l = tid & 63, w = tid >> 6;
  const int l16 = l & 15, sub = l >> 4;
  const int j = blockIdx.x * 16 + w * 4 + sub;
  const float4* p4 = (const float4*)p;
  float4 v0 = p4[j * 32 + 2 * l16];
  float4 v1 = p4[j * 32 + 2 * l16 + 1];
  int2 st;
  st.x = pk_fp8x4(v0.x * FP8_SCALE, v0.y * FP8_SCALE, v0.z * FP8_SCALE, v0.w * FP8_SCALE);
  st.y = pk_fp8x4(v1.x * FP8_SCALE, v1.y * FP8_SCALE, v1.z * FP8_SCALE, v1.w * FP8_SCALE);
  *(int2*)(pb + (size_t)j * 128 + 8 * l16) = st;
  float np2 = v0.x * v0.x;
  np2 = fmaf(v0.y, v0.y, np2); np2 = fmaf(v0.z, v0.z, np2); np2 = fmaf(v0.w, v0.w, np2);
  np2 = fmaf(v1.x, v1.x, np2); np2 = fmaf(v1.y, v1.y, np2);
  np2 = fmaf(v1.z, v1.z, np2); np2 = fmaf(v1.w, v1.w, np2);
  const float4 sx0 = *(const float4*)&sum_x[8 * l16];
  const float4 sx1 = *(const float4*)&sum_x[8 * l16 + 4];
  float sd = v0.x * sx0.x;
  sd = fmaf(v0.y, sx0.y, sd); sd = fmaf(v0.z, sx0.z, sd); sd = fmaf(v0.w, sx0.w, sd);
  sd = fmaf(v1.x, sx1.x, sd); sd = fmaf(v1.y, sx1.y, sd);
  sd = fmaf(v1.z, sx1.z, sd); sd = fmaf(v1.w, sx1.w, sd);
#pragma unroll
  for (int off = 8; off; off >>= 1) {
    np2 += __shfl_down(np2, off);
    sd += __shfl_down(sd, off);
  }
  if (l16 == 0) {
    float ssd = *sum_nx2 + (float)N * np2 - 2.f * sd;
    float npn = sqrtf(np2);
    float cfi = 1.f / (npn * sqrtf(ssd));
    float4 cc;
    cc.x = (1.f + np2) * cfi * (1.0f / 256.0f);
    cc.y = np2 * cfi;
    cc.z = np2;
    cc.w = 256.0f * np2 / (1.f + np2);
    colc[j] = cc;
    psiA[j] = asinf(KCONST * (1.f - np2) / npn);
  }
}

// ---------------------------------------------------------------------------
// pair_mfma v7: fp8 e4m3 staging. 512 blocks; block b: rowTile b>>2 (128
// rows; xs 16 KB staged once), walks 8 colTiles of 64 cols (ps 2x8 KB
// double-buffer). LDS 32 KB -> 4-5 blocks/CU (the occupancy that was the
// binding constraint at 64 KB). 8-quad XOR swizzle, ds_read_b64 fragments,
// dot recovered from the x256 product scale via constant folds. Exact
// early-out epilogue; block partial -> atomicAdd(out) (zeroed by prep_x).
// ---------------------------------------------------------------------------
__global__ __launch_bounds__(256, 4) void pair_mfma(
    const unsigned char* __restrict__ xb, const unsigned char* __restrict__ pb,
    const int* __restrict__ labels, const float* __restrict__ nx2p,
    const float4* __restrict__ colc, const float* __restrict__ psiA,
    float* __restrict__ out, float invN) {
  __shared__ float4 xs4[1024];     // 128 rows x 8 quads (16B), swizzled
  __shared__ float4 ps4[2][512];   // 2 x (64 rows x 8 quads), swizzled
  __shared__ float wred[4];

  const int b = blockIdx.x;
  const int rowTile = b >> 2;   // 0..127
  const int cg = b & 3;         // colGroup: colTiles cg*8 .. cg*8+7
  const int row0 = rowTile * 128;

  const int tid = threadIdx.x;
  const int l = tid & 63;
  const int w = tid >> 6;
  const float4* xg = (const float4*)(xb + (size_t)row0 * 128);

  // stage xs once: slot (r,ql) <- source quad (r, ql ^ (r&7)); 8 quads/row
#pragma unroll
  for (int ci = w; ci < 16; ci += 4) {
    int qi = ci * 64 + l;
    int r = qi >> 3, ql = qi & 7;
    ASYNC_COPY16(xg + r * 8 + (ql ^ (r & 7)), xs4 + ci * 64);
  }
  // stage ps[0] for colTile cg*8
  {
    const float4* pg = (const float4*)(pb + (size_t)(cg * 8) * 64 * 128);
#pragma unroll
    for (int ci = w; ci < 8; ci += 4) {
      int qi = ci * 64 + l;
      int r = qi >> 3, ql = qi & 7;
      ASYNC_COPY16(pg + r * 8 + (ql ^ (r & 7)), ps4[0] + ci * 64);
    }
  }

  const int m = tid & 15;
  const int q = (tid >> 4) & 3;
  const int wr = (w & 1) * 64;   // wave's row offset (64 rows)
  const int wc = (w >> 1) * 32;  // wave's col offset (32 cols)

  // row-side constants: fixed across all 8 tile-iterations
  f32x4 rnp4v[4];
  int4 lb4v[4];
#pragma unroll
  for (int r = 0; r < 4; ++r) {
    rnp4v[r] = __builtin_bit_cast(f32x4, *(const float4*)&nx2p[row0 + wr + r * 16 + q * 4]);
    lb4v[r] = *(const int4*)&labels[row0 + wr + r * 16 + q * 4];
  }

  // register-prefetch colc for iter 0
  float4 ccur0 = colc[(cg * 8) * 64 + wc + m];
  float4 ccur1 = colc[(cg * 8) * 64 + wc + 16 + m];

  const char* xsb = (const char*)xs4;
  float ssum = 0.f;
#pragma unroll
  for (int it = 0; it < 8; ++it) {
    __syncthreads();  // drains the ps prefetch issued last iter (landed)
    const int cur = it & 1;
    if (it < 7) {  // prefetch next colTile into the other buffer
      const float4* pg = (const float4*)(pb + (size_t)(cg * 8 + it + 1) * 64 * 128);
#pragma unroll
      for (int ci = w; ci < 8; ci += 4) {
        int qi = ci * 64 + l;
        int r = qi >> 3, ql = qi & 7;
        ASYNC_COPY16(pg + r * 8 + (ql ^ (r & 7)), ps4[cur ^ 1] + ci * 64);
      }
    }
    float4 cnext0, cnext1;
    if (it < 7) {
      cnext0 = colc[(cg * 8 + it + 1) * 64 + wc + m];
      cnext1 = colc[(cg * 8 + it + 1) * 64 + wc + 16 + m];
    }

    // ---- compute 128x64 tile: 4x2 frags/wave, 4 k-steps (fp8 K=32) ----
    const char* psb = (const char*)ps4[cur];
    f32x4 acc[4][2];
#pragma unroll
    for (int r = 0; r < 4; ++r) {
      acc[r][0] = (f32x4)(0.f);
      acc[r][1] = (f32x4)(0.f);
    }
#pragma unroll
    for (int s = 0; s < 4; ++s) {
      const int g = s * 4 + q;                 // 8B k-granule index (0..15)
      const int gq = g >> 1, gh = (g & 1) << 3;
      long a[4], bf[2];
#pragma unroll
      for (int c = 0; c < 2; ++c) {
        const int row = wc + c * 16 + m;
        bf[c] = *(const long*)(psb + row * 128 + ((gq ^ (row & 7)) << 4) + gh);
      }
#pragma unroll
      for (int r = 0; r < 4; ++r) {
        const int row = wr + r * 16 + m;
        a[r] = *(const long*)(xsb + row * 128 + ((gq ^ (row & 7)) << 4) + gh);
      }
#pragma unroll
      for (int r = 0; r < 4; ++r)
#pragma unroll
        for (int c = 0; c < 2; ++c)
          acc[r][c] = __builtin_amdgcn_mfma_f32_16x16x32_fp8_fp8(a[r], bf[c], acc[r][c], 0, 0, 0);
    }

    // ---- fused epilogue with exact early-out (dotRaw = 256*dot) ----
    const int ct0 = (cg * 8 + it) * 64;
#pragma unroll
    for (int c = 0; c < 2; ++c) {
      const int col = ct0 + wc + c * 16 + m;
      const float4 cc = (c == 0) ? ccur0 : ccur1;  // (Ac/256, Bc, np2, 256*Tc)
      const float Tc = cc.w;
#pragma unroll
      for (int r = 0; r < 4; ++r) {
        const f32x4 rnp4 = rnp4v[r];
        const int4 lb4 = lb4v[r];
        const f32x4 dv = acc[r][c];
        float e0 = fmaf(-Tc, rnp4[0], dv[0]);
        float e1 = fmaf(-Tc, rnp4[1], dv[1]);
        float e2 = fmaf(-Tc, rnp4[2], dv[2]);
        float e3 = fmaf(-Tc, rnp4[3], dv[3]);
        float hm = fmaxf(fmaxf(e0, e1), fmaxf(e2, e3));
        bool h = (hm > 0.f) | (col == lb4.x) | (col == lb4.y) |
                 (col == lb4.z) | (col == lb4.w);
        if (__builtin_expect(h, 0)) {
          const float psi = psiA[col];
          const float C1 = 1.f + psi;
          const float omnp2 = 1.f - cc.z;
#pragma unroll
          for (int g2 = 0; g2 < 4; ++g2) {
            float rnp = rnp4[g2];
            float dotRaw = dv[g2];
            int lb = (g2 == 0) ? lb4.x : (g2 == 1) ? lb4.y : (g2 == 2) ? lb4.z : lb4.w;
            float den2 = fmaf(-INV_TWO_OVER_SQ, dotRaw, fmaf(cc.z, rnp, omnp2));
            float nump = fmaf(dotRaw, cc.x, -cc.y * rnp);
            float u = nump * __builtin_amdgcn_rsqf(den2);
            u = __builtin_amdgcn_fmed3f(u, -1.f, 1.f);
            float ax = fabsf(u);
            float rt = __builtin_amdgcn_sqrtf(1.f - ax);
            float poly = fmaf(fmaf(fmaf(-0.0187293f, ax, 0.0742610f), ax, -0.2121144f),
                              ax, 1.5707288f);
            float ac = rt * poly;
            ac = (u >= 0.f) ? ac : 3.14159265358979f - ac;
            float neg = __builtin_amdgcn_fmed3f(C1 - ac, 0.f, 1.f);
            float pos = fmaxf(0.f, ac - psi);
            ssum += (col == lb) ? pos : neg;
          }
        }
      }
    }
    if (it < 7) {
      ccur0 = cnext0;
      ccur1 = cnext1;
    }
  }

#pragma unroll
  for (int off = 32; off; off >>= 1) ssum += __shfl_down(ssum, off);
  if (l == 0) wred[w] = ssum;
  __syncthreads();
  if (tid == 0)
    atomicAdd(out, (wred[0] + wred[1] + wred[2] + wred[3]) * invN);
}

extern "C" void kernel_launch(void* const* d_in, const int* in_sizes, int n_in,
                              void* d_out, int out_size, void* d_ws, size_t ws_size,
                              hipStream_t stream) {
  const float* x = (const float*)d_in[0];
  const float* p = (const float*)d_in[1];
  const int* labels = (const int*)d_in[2];
  float* out = (float*)d_out;
  const int N = in_sizes[2];          // 16384
  const int M = in_sizes[1] / D_DIM;  // 2048

  float* ws = (float*)d_ws;
  float* nx2p = ws;                                  // N  (1 + ||x||^2)
  float4* colc = (float4*)(ws + N);                  // M float4
  float* psiA = ws + N + 4 * M;                      // M
  unsigned char* xb = (unsigned char*)(ws + N + 5 * M);             // N*128 fp8
  unsigned char* pb = (unsigned char*)(ws + N + 5 * M + 32 * N);    // M*128 fp8
  float* pSumX = ws + N + 5 * M + 32 * N + 32 * M;   // 256*128
  float* pS2 = pSumX + 256 * 128;                    // 256
  float* sum_x = pS2 + 256;                          // 128
  float* sum_nx2 = sum_x + 128;                      // 4

  prep_x<<<256, 256, 0, stream>>>(x, xb, nx2p, pSumX, pS2, out, N);
  merge_sums<<<1, 1024, 0, stream>>>(pSumX, pS2, sum_x, sum_nx2);
  prep_p<<<M / 16, 256, 0, stream>>>(p, pb, sum_x, sum_nx2, colc, psiA, M, N);

  pair_mfma<<<512, 256, 0, stream>>>(xb, pb, labels, nx2p, colc, psiA, out,
                                     1.0f / (float)N);
}